// Round 1
// baseline (9884.322 us; speedup 1.0000x reference)
//
#include <hip/hip_runtime.h>
#include <math.h>

#define NN 100000
#define NE 3200000
#define FIN 64
#define HID 20
#define NG 128
#define NC 10

// ---------------- Kernel 1: t = x @ W1a  (100000x64 @ 64x20) ----------------
__global__ __launch_bounds__(256) void k_in_gemm(const float* __restrict__ x,
                                                 const float* __restrict__ W,
                                                 float* __restrict__ t) {
    __shared__ float sW[FIN * HID];
    for (int i = threadIdx.x; i < FIN * HID; i += blockDim.x) sW[i] = W[i];
    __syncthreads();
    int node = blockIdx.x * blockDim.x + threadIdx.x;
    if (node >= NN) return;
    float acc[HID];
#pragma unroll
    for (int f = 0; f < HID; ++f) acc[f] = 0.f;
    const float4* xr = (const float4*)(x + node * FIN);
#pragma unroll 4
    for (int q = 0; q < FIN / 4; ++q) {
        float4 xv = xr[q];
        int k = q * 4;
#pragma unroll
        for (int f = 0; f < HID; ++f) acc[f] += xv.x * sW[(k + 0) * HID + f];
#pragma unroll
        for (int f = 0; f < HID; ++f) acc[f] += xv.y * sW[(k + 1) * HID + f];
#pragma unroll
        for (int f = 0; f < HID; ++f) acc[f] += xv.z * sW[(k + 2) * HID + f];
#pragma unroll
        for (int f = 0; f < HID; ++f) acc[f] += xv.w * sW[(k + 3) * HID + f];
    }
    float4* tr = (float4*)(t + node * HID);
#pragma unroll
    for (int q = 0; q < HID / 4; ++q) {
        float4 v;
        v.x = acc[q * 4 + 0]; v.y = acc[q * 4 + 1];
        v.z = acc[q * 4 + 2]; v.w = acc[q * 4 + 3];
        tr[q] = v;
    }
}

// ---------------- Scatter-add: agg[dst] += t[src] * w ----------------
__global__ __launch_bounds__(256) void k_scatter(const int* __restrict__ src,
                                                 const int* __restrict__ dst,
                                                 const float* __restrict__ w,
                                                 const float* __restrict__ t,
                                                 float* __restrict__ agg) {
    int e = blockIdx.x * blockDim.x + threadIdx.x;
    if (e >= NE) return;
    int s = src[e];
    int d = dst[e];
    float wt = w[e];
    const float4* tr = (const float4*)(t + (long)s * HID);
    float* ar = agg + (long)d * HID;
#pragma unroll
    for (int q = 0; q < HID / 4; ++q) {
        float4 v = tr[q];
        atomicAdd(ar + q * 4 + 0, v.x * wt);
        atomicAdd(ar + q * 4 + 1, v.y * wt);
        atomicAdd(ar + q * 4 + 2, v.z * wt);
        atomicAdd(ar + q * 4 + 3, v.w * wt);
    }
}

// ---------------- Node update ----------------
// z1 = relu(agg + ba); z2 = relu(z1 @ Wb + bb); h = z2 / max(||z2||, eps); (relu no-op)
// if !LAST: out = h @ Wnext      (premultiplied message for next layer)
// if  LAST: out = h              (h3, consumed by pooling)
template <bool LAST>
__global__ __launch_bounds__(256) void k_node(const float* __restrict__ agg,
                                              const float* __restrict__ ba,
                                              const float* __restrict__ Wb,
                                              const float* __restrict__ bb,
                                              const float* __restrict__ Wnext,
                                              float* __restrict__ out) {
    __shared__ float sWb[HID * HID];
    __shared__ float sWn[HID * HID];
    __shared__ float sba[HID], sbb[HID];
    for (int i = threadIdx.x; i < HID * HID; i += blockDim.x) {
        sWb[i] = Wb[i];
        if (!LAST) sWn[i] = Wnext[i];
    }
    if (threadIdx.x < HID) {
        sba[threadIdx.x] = ba[threadIdx.x];
        sbb[threadIdx.x] = bb[threadIdx.x];
    }
    __syncthreads();
    int node = blockIdx.x * blockDim.x + threadIdx.x;
    if (node >= NN) return;

    float z1[HID];
    const float4* ar = (const float4*)(agg + (long)node * HID);
#pragma unroll
    for (int q = 0; q < HID / 4; ++q) {
        float4 v = ar[q];
        z1[q * 4 + 0] = v.x; z1[q * 4 + 1] = v.y;
        z1[q * 4 + 2] = v.z; z1[q * 4 + 3] = v.w;
    }
#pragma unroll
    for (int f = 0; f < HID; ++f) z1[f] = fmaxf(z1[f] + sba[f], 0.f);

    float z2[HID];
#pragma unroll
    for (int fo = 0; fo < HID; ++fo) {
        float a = sbb[fo];
#pragma unroll
        for (int k = 0; k < HID; ++k) a += z1[k] * sWb[k * HID + fo];
        z2[fo] = fmaxf(a, 0.f);
    }

    float ss = 0.f;
#pragma unroll
    for (int f = 0; f < HID; ++f) ss += z2[f] * z2[f];
    float nrm = sqrtf(ss);
    float scale = 1.f / fmaxf(nrm, 1e-12f);
#pragma unroll
    for (int f = 0; f < HID; ++f) z2[f] *= scale;  // h (>=0, final relu no-op)

    float res[HID];
    if (LAST) {
#pragma unroll
        for (int f = 0; f < HID; ++f) res[f] = z2[f];
    } else {
#pragma unroll
        for (int fo = 0; fo < HID; ++fo) {
            float a = 0.f;
#pragma unroll
            for (int k = 0; k < HID; ++k) a += z2[k] * sWn[k * HID + fo];
            res[fo] = a;
        }
    }
    float4* orow = (float4*)(out + (long)node * HID);
#pragma unroll
    for (int q = 0; q < HID / 4; ++q) {
        float4 v;
        v.x = res[q * 4 + 0]; v.y = res[q * 4 + 1];
        v.z = res[q * 4 + 2]; v.w = res[q * 4 + 3];
        orow[q] = v;
    }
}

// ---------------- Pooling + head (one block per graph; batch is sorted) ----------------
__global__ __launch_bounds__(256) void k_pool(const float* __restrict__ h,
                                              const int* __restrict__ batch,
                                              const float* __restrict__ Wlin,
                                              const float* __restrict__ blin,
                                              float* __restrict__ out) {
    int g = blockIdx.x;
    __shared__ int s_lo, s_hi;
    if (threadIdx.x == 0) {
        int a = 0, b = NN;
        while (a < b) { int m = (a + b) >> 1; if (batch[m] < g) a = m + 1; else b = m; }
        s_lo = a;
        b = NN;  // a already >= lo
        while (a < b) { int m = (a + b) >> 1; if (batch[m] < g + 1) a = m + 1; else b = m; }
        s_hi = a;
    }
    __syncthreads();
    int lo = s_lo, hi = s_hi;

    float sm[HID], mx[HID];
#pragma unroll
    for (int f = 0; f < HID; ++f) { sm[f] = 0.f; mx[f] = 0.f; }

    for (int i = lo + threadIdx.x; i < hi; i += blockDim.x) {
        const float4* hr = (const float4*)(h + (long)i * HID);
#pragma unroll
        for (int q = 0; q < HID / 4; ++q) {
            float4 v = hr[q];
            sm[q * 4 + 0] += v.x; mx[q * 4 + 0] = fmaxf(mx[q * 4 + 0], v.x);
            sm[q * 4 + 1] += v.y; mx[q * 4 + 1] = fmaxf(mx[q * 4 + 1], v.y);
            sm[q * 4 + 2] += v.z; mx[q * 4 + 2] = fmaxf(mx[q * 4 + 2], v.z);
            sm[q * 4 + 3] += v.w; mx[q * 4 + 3] = fmaxf(mx[q * 4 + 3], v.w);
        }
    }

    // wave-level reduce (wave = 64 lanes)
#pragma unroll
    for (int f = 0; f < HID; ++f) {
        float s = sm[f], m = mx[f];
        for (int off = 32; off > 0; off >>= 1) {
            s += __shfl_down(s, off);
            m = fmaxf(m, __shfl_down(m, off));
        }
        sm[f] = s; mx[f] = m;
    }

    __shared__ float psum[4][HID], pmax[4][HID];
    int wave = threadIdx.x >> 6;
    int lane = threadIdx.x & 63;
    if (lane == 0) {
#pragma unroll
        for (int f = 0; f < HID; ++f) { psum[wave][f] = sm[f]; pmax[wave][f] = mx[f]; }
    }
    __syncthreads();

    __shared__ float fsum[HID], fmax_[HID];
    if (threadIdx.x < HID) {
        int f = threadIdx.x;
        float s = psum[0][f] + psum[1][f] + psum[2][f] + psum[3][f];
        float m = fmaxf(fmaxf(pmax[0][f], pmax[1][f]), fmaxf(pmax[2][f], pmax[3][f]));
        fsum[f] = s; fmax_[f] = m;
    }
    __syncthreads();

    if (threadIdx.x < NC) {
        int c = threadIdx.x;
        float cnt = (float)(hi - lo);
        float inv = 1.f / fmaxf(cnt, 1.f);
        float o = blin[c];
#pragma unroll
        for (int f = 0; f < HID; ++f) {
            o += fmax_[f] * Wlin[f * NC + c];
            o += (fsum[f] * inv) * Wlin[(HID + f) * NC + c];
        }
        out[g * NC + c] = o;
    }
}

extern "C" void kernel_launch(void* const* d_in, const int* in_sizes, int n_in,
                              void* d_out, int out_size, void* d_ws, size_t ws_size,
                              hipStream_t stream) {
    const float* x   = (const float*)d_in[0];
    const int*   ei  = (const int*)d_in[1];
    const int*   bat = (const int*)d_in[2];
    const float* ew  = (const float*)d_in[3];
    const float* W1a = (const float*)d_in[4];
    const float* b1a = (const float*)d_in[5];
    const float* W1b = (const float*)d_in[6];
    const float* b1b = (const float*)d_in[7];
    const float* W2a = (const float*)d_in[8];
    const float* b2a = (const float*)d_in[9];
    const float* W2b = (const float*)d_in[10];
    const float* b2b = (const float*)d_in[11];
    const float* W3a = (const float*)d_in[12];
    const float* b3a = (const float*)d_in[13];
    const float* W3b = (const float*)d_in[14];
    const float* b3b = (const float*)d_in[15];
    const float* Wlin = (const float*)d_in[16];
    const float* blin = (const float*)d_in[17];

    const int* src = ei;        // edge_index[0]
    const int* dst = ei + NE;   // edge_index[1]

    float* T = (float*)d_ws;            // NN*HID floats (messages t / h3)
    float* A = T + (size_t)NN * HID;    // NN*HID floats (aggregation)

    dim3 blk(256);
    dim3 gN((NN + 255) / 256);
    dim3 gE((NE + 255) / 256);

    // Layer 1
    k_in_gemm<<<gN, blk, 0, stream>>>(x, W1a, T);
    hipMemsetAsync(A, 0, (size_t)NN * HID * sizeof(float), stream);
    k_scatter<<<gE, blk, 0, stream>>>(src, dst, ew, T, A);
    k_node<false><<<gN, blk, 0, stream>>>(A, b1a, W1b, b1b, W2a, T);

    // Layer 2
    hipMemsetAsync(A, 0, (size_t)NN * HID * sizeof(float), stream);
    k_scatter<<<gE, blk, 0, stream>>>(src, dst, ew, T, A);
    k_node<false><<<gN, blk, 0, stream>>>(A, b2a, W2b, b2b, W3a, T);

    // Layer 3
    hipMemsetAsync(A, 0, (size_t)NN * HID * sizeof(float), stream);
    k_scatter<<<gE, blk, 0, stream>>>(src, dst, ew, T, A);
    k_node<true><<<gN, blk, 0, stream>>>(A, b3a, W3b, b3b, nullptr, T);

    // Pool + head
    k_pool<<<NG, blk, 0, stream>>>(T, bat, Wlin, blin, (float*)d_out);
}

// Round 2
// 649.404 us; speedup vs baseline: 15.2206x; 15.2206x over previous
//
#include <hip/hip_runtime.h>
#include <math.h>

#define NN 100000
#define NE 3200000
#define FIN 64
#define HID 20
#define NG 128
#define NC 10

#define SCAN_ELEMS 1024
#define SCAN_NBLK ((NN + SCAN_ELEMS - 1) / SCAN_ELEMS)  // 98

// ---------------- t = x @ W1a  (100000x64 @ 64x20) ----------------
__global__ __launch_bounds__(256) void k_in_gemm(const float* __restrict__ x,
                                                 const float* __restrict__ W,
                                                 float* __restrict__ t) {
    __shared__ float sW[FIN * HID];
    for (int i = threadIdx.x; i < FIN * HID; i += blockDim.x) sW[i] = W[i];
    __syncthreads();
    int node = blockIdx.x * blockDim.x + threadIdx.x;
    if (node >= NN) return;
    float acc[HID];
#pragma unroll
    for (int f = 0; f < HID; ++f) acc[f] = 0.f;
    const float4* xr = (const float4*)(x + node * FIN);
#pragma unroll 4
    for (int q = 0; q < FIN / 4; ++q) {
        float4 xv = xr[q];
        int k = q * 4;
#pragma unroll
        for (int f = 0; f < HID; ++f) acc[f] += xv.x * sW[(k + 0) * HID + f];
#pragma unroll
        for (int f = 0; f < HID; ++f) acc[f] += xv.y * sW[(k + 1) * HID + f];
#pragma unroll
        for (int f = 0; f < HID; ++f) acc[f] += xv.z * sW[(k + 2) * HID + f];
#pragma unroll
        for (int f = 0; f < HID; ++f) acc[f] += xv.w * sW[(k + 3) * HID + f];
    }
    float4* tr = (float4*)(t + node * HID);
#pragma unroll
    for (int q = 0; q < HID / 4; ++q) {
        float4 v;
        v.x = acc[q * 4 + 0]; v.y = acc[q * 4 + 1];
        v.z = acc[q * 4 + 2]; v.w = acc[q * 4 + 3];
        tr[q] = v;
    }
}

// ================= CSR build =================
__global__ __launch_bounds__(256) void k_hist(const int* __restrict__ dst,
                                              int* __restrict__ cnt) {
    int e = blockIdx.x * blockDim.x + threadIdx.x;
    if (e >= NE) return;
    atomicAdd(&cnt[dst[e]], 1);
}

__global__ __launch_bounds__(256) void k_breduce(const int* __restrict__ cnt,
                                                 int* __restrict__ bsum) {
    int b = blockIdx.x;
    int t = threadIdx.x;
    int base = b * SCAN_ELEMS;
    int s = 0;
    for (int i = t; i < SCAN_ELEMS; i += 256) {
        int idx = base + i;
        if (idx < NN) s += cnt[idx];
    }
    __shared__ int red[256];
    red[t] = s;
    __syncthreads();
    for (int off = 128; off > 0; off >>= 1) {
        if (t < off) red[t] += red[t + off];
        __syncthreads();
    }
    if (t == 0) bsum[b] = red[0];
}

__global__ __launch_bounds__(256) void k_bscan(const int* __restrict__ cnt,
                                               const int* __restrict__ bsum,
                                               int* __restrict__ off) {
    int b = blockIdx.x, t = threadIdx.x;
    __shared__ int s_base;
    if (t == 0) {
        int s = 0;
        for (int j = 0; j < b; ++j) s += bsum[j];
        s_base = s;
    }
    __shared__ int tsum[256];
    int base_i = b * SCAN_ELEMS + t * 4;
    int v[4];
    int s = 0;
#pragma unroll
    for (int k = 0; k < 4; ++k) {
        int idx = base_i + k;
        v[k] = (idx < NN) ? cnt[idx] : 0;
        s += v[k];
    }
    tsum[t] = s;
    __syncthreads();
    for (int d = 1; d < 256; d <<= 1) {
        int add = (t >= d) ? tsum[t - d] : 0;
        __syncthreads();
        tsum[t] += add;
        __syncthreads();
    }
    int excl = tsum[t] - s + s_base;
#pragma unroll
    for (int k = 0; k < 4; ++k) {
        int idx = base_i + k;
        if (idx < NN) off[idx] = excl;
        excl += v[k];
    }
    if (b == 0 && t == 0) off[NN] = NE;
}

__global__ __launch_bounds__(256) void k_build(const int* __restrict__ src,
                                               const int* __restrict__ dst,
                                               const float* __restrict__ w,
                                               int* __restrict__ cursor,
                                               int2* __restrict__ csr) {
    int e = blockIdx.x * blockDim.x + threadIdx.x;
    if (e >= NE) return;
    int d = dst[e];
    int pos = atomicAdd(&cursor[d], 1);
    csr[pos] = make_int2(src[e], __float_as_int(w[e]));
}

// ---------------- Aggregation: 4 lanes per node, no atomics ----------------
__global__ __launch_bounds__(256) void k_agg(const int* __restrict__ off,
                                             const int2* __restrict__ csr,
                                             const float* __restrict__ t,
                                             float* __restrict__ agg) {
    int tid = blockIdx.x * blockDim.x + threadIdx.x;
    int node = tid >> 2;
    int j = tid & 3;
    if (node >= NN) return;
    int lo = off[node], hi = off[node + 1];
    float acc[HID];
#pragma unroll
    for (int f = 0; f < HID; ++f) acc[f] = 0.f;
    for (int i = lo + j; i < hi; i += 4) {
        int2 pr = csr[i];
        int s = pr.x;
        float wt = __int_as_float(pr.y);
        const float4* tr = (const float4*)(t + (long)s * HID);
#pragma unroll
        for (int q = 0; q < HID / 4; ++q) {
            float4 v = tr[q];
            acc[q * 4 + 0] += wt * v.x;
            acc[q * 4 + 1] += wt * v.y;
            acc[q * 4 + 2] += wt * v.z;
            acc[q * 4 + 3] += wt * v.w;
        }
    }
    // reduce across the 4 lanes of the quad
#pragma unroll
    for (int f = 0; f < HID; ++f) {
        acc[f] += __shfl_xor(acc[f], 1);
        acc[f] += __shfl_xor(acc[f], 2);
    }
    // each lane writes 5 contiguous floats
    float* ar = agg + (long)node * HID + j * 5;
#pragma unroll
    for (int k = 0; k < 5; ++k) ar[k] = acc[j * 5 + k];
}

// ---------------- Node update (may run in-place: out == agg) ----------------
template <bool LAST>
__global__ __launch_bounds__(256) void k_node(const float* agg,
                                              const float* __restrict__ ba,
                                              const float* __restrict__ Wb,
                                              const float* __restrict__ bb,
                                              const float* __restrict__ Wnext,
                                              float* out) {
    __shared__ float sWb[HID * HID];
    __shared__ float sWn[HID * HID];
    __shared__ float sba[HID], sbb[HID];
    for (int i = threadIdx.x; i < HID * HID; i += blockDim.x) {
        sWb[i] = Wb[i];
        if (!LAST) sWn[i] = Wnext[i];
    }
    if (threadIdx.x < HID) {
        sba[threadIdx.x] = ba[threadIdx.x];
        sbb[threadIdx.x] = bb[threadIdx.x];
    }
    __syncthreads();
    int node = blockIdx.x * blockDim.x + threadIdx.x;
    if (node >= NN) return;

    float z1[HID];
    const float4* ar = (const float4*)(agg + (long)node * HID);
#pragma unroll
    for (int q = 0; q < HID / 4; ++q) {
        float4 v = ar[q];
        z1[q * 4 + 0] = v.x; z1[q * 4 + 1] = v.y;
        z1[q * 4 + 2] = v.z; z1[q * 4 + 3] = v.w;
    }
#pragma unroll
    for (int f = 0; f < HID; ++f) z1[f] = fmaxf(z1[f] + sba[f], 0.f);

    float z2[HID];
#pragma unroll
    for (int fo = 0; fo < HID; ++fo) {
        float a = sbb[fo];
#pragma unroll
        for (int k = 0; k < HID; ++k) a += z1[k] * sWb[k * HID + fo];
        z2[fo] = fmaxf(a, 0.f);
    }

    float ss = 0.f;
#pragma unroll
    for (int f = 0; f < HID; ++f) ss += z2[f] * z2[f];
    float scale = 1.f / fmaxf(sqrtf(ss), 1e-12f);
#pragma unroll
    for (int f = 0; f < HID; ++f) z2[f] *= scale;

    float res[HID];
    if (LAST) {
#pragma unroll
        for (int f = 0; f < HID; ++f) res[f] = z2[f];
    } else {
#pragma unroll
        for (int fo = 0; fo < HID; ++fo) {
            float a = 0.f;
#pragma unroll
            for (int k = 0; k < HID; ++k) a += z2[k] * sWn[k * HID + fo];
            res[fo] = a;
        }
    }
    float4* orow = (float4*)(out + (long)node * HID);
#pragma unroll
    for (int q = 0; q < HID / 4; ++q) {
        float4 v;
        v.x = res[q * 4 + 0]; v.y = res[q * 4 + 1];
        v.z = res[q * 4 + 2]; v.w = res[q * 4 + 3];
        orow[q] = v;
    }
}

// ---------------- Fallback atomic scatter (if ws too small) ----------------
__global__ __launch_bounds__(256) void k_scatter(const int* __restrict__ src,
                                                 const int* __restrict__ dst,
                                                 const float* __restrict__ w,
                                                 const float* __restrict__ t,
                                                 float* __restrict__ agg) {
    int e = blockIdx.x * blockDim.x + threadIdx.x;
    if (e >= NE) return;
    int s = src[e];
    int d = dst[e];
    float wt = w[e];
    const float4* tr = (const float4*)(t + (long)s * HID);
    float* ar = agg + (long)d * HID;
#pragma unroll
    for (int q = 0; q < HID / 4; ++q) {
        float4 v = tr[q];
        atomicAdd(ar + q * 4 + 0, v.x * wt);
        atomicAdd(ar + q * 4 + 1, v.y * wt);
        atomicAdd(ar + q * 4 + 2, v.z * wt);
        atomicAdd(ar + q * 4 + 3, v.w * wt);
    }
}

// ---------------- Pooling + head ----------------
__global__ __launch_bounds__(256) void k_pool(const float* __restrict__ h,
                                              const int* __restrict__ batch,
                                              const float* __restrict__ Wlin,
                                              const float* __restrict__ blin,
                                              float* __restrict__ out) {
    int g = blockIdx.x;
    __shared__ int s_lo, s_hi;
    if (threadIdx.x == 0) {
        int a = 0, b = NN;
        while (a < b) { int m = (a + b) >> 1; if (batch[m] < g) a = m + 1; else b = m; }
        s_lo = a;
        b = NN;
        while (a < b) { int m = (a + b) >> 1; if (batch[m] < g + 1) a = m + 1; else b = m; }
        s_hi = a;
    }
    __syncthreads();
    int lo = s_lo, hi = s_hi;

    float sm[HID], mx[HID];
#pragma unroll
    for (int f = 0; f < HID; ++f) { sm[f] = 0.f; mx[f] = 0.f; }

    for (int i = lo + threadIdx.x; i < hi; i += blockDim.x) {
        const float4* hr = (const float4*)(h + (long)i * HID);
#pragma unroll
        for (int q = 0; q < HID / 4; ++q) {
            float4 v = hr[q];
            sm[q * 4 + 0] += v.x; mx[q * 4 + 0] = fmaxf(mx[q * 4 + 0], v.x);
            sm[q * 4 + 1] += v.y; mx[q * 4 + 1] = fmaxf(mx[q * 4 + 1], v.y);
            sm[q * 4 + 2] += v.z; mx[q * 4 + 2] = fmaxf(mx[q * 4 + 2], v.z);
            sm[q * 4 + 3] += v.w; mx[q * 4 + 3] = fmaxf(mx[q * 4 + 3], v.w);
        }
    }

#pragma unroll
    for (int f = 0; f < HID; ++f) {
        float s = sm[f], m = mx[f];
        for (int off = 32; off > 0; off >>= 1) {
            s += __shfl_down(s, off);
            m = fmaxf(m, __shfl_down(m, off));
        }
        sm[f] = s; mx[f] = m;
    }

    __shared__ float psum[4][HID], pmax[4][HID];
    int wave = threadIdx.x >> 6;
    int lane = threadIdx.x & 63;
    if (lane == 0) {
#pragma unroll
        for (int f = 0; f < HID; ++f) { psum[wave][f] = sm[f]; pmax[wave][f] = mx[f]; }
    }
    __syncthreads();

    __shared__ float fsum[HID], fmax_[HID];
    if (threadIdx.x < HID) {
        int f = threadIdx.x;
        fsum[f] = psum[0][f] + psum[1][f] + psum[2][f] + psum[3][f];
        fmax_[f] = fmaxf(fmaxf(pmax[0][f], pmax[1][f]), fmaxf(pmax[2][f], pmax[3][f]));
    }
    __syncthreads();

    if (threadIdx.x < NC) {
        int c = threadIdx.x;
        float cnt = (float)(hi - lo);
        float inv = 1.f / fmaxf(cnt, 1.f);
        float o = blin[c];
#pragma unroll
        for (int f = 0; f < HID; ++f) {
            o += fmax_[f] * Wlin[f * NC + c];
            o += (fsum[f] * inv) * Wlin[(HID + f) * NC + c];
        }
        out[g * NC + c] = o;
    }
}

extern "C" void kernel_launch(void* const* d_in, const int* in_sizes, int n_in,
                              void* d_out, int out_size, void* d_ws, size_t ws_size,
                              hipStream_t stream) {
    const float* x   = (const float*)d_in[0];
    const int*   ei  = (const int*)d_in[1];
    const int*   bat = (const int*)d_in[2];
    const float* ew  = (const float*)d_in[3];
    const float* W1a = (const float*)d_in[4];
    const float* b1a = (const float*)d_in[5];
    const float* W1b = (const float*)d_in[6];
    const float* b1b = (const float*)d_in[7];
    const float* W2a = (const float*)d_in[8];
    const float* b2a = (const float*)d_in[9];
    const float* W2b = (const float*)d_in[10];
    const float* b2b = (const float*)d_in[11];
    const float* W3a = (const float*)d_in[12];
    const float* b3a = (const float*)d_in[13];
    const float* W3b = (const float*)d_in[14];
    const float* b3b = (const float*)d_in[15];
    const float* Wlin = (const float*)d_in[16];
    const float* blin = (const float*)d_in[17];

    const int* src = ei;
    const int* dst = ei + NE;

    dim3 blk(256);
    dim3 gN((NN + 255) / 256);
    dim3 gE((NE + 255) / 256);
    dim3 gQ(((size_t)NN * 4 + 255) / 256);

    // workspace layout (CSR path): T0, T1, cnt/cursor, off, bsum, csr
    size_t szT   = (size_t)NN * HID * sizeof(float);           // 8 MB
    size_t szCnt = (size_t)NN * sizeof(int);                   // 400 KB
    size_t szOff = (size_t)(NN + 1) * sizeof(int);
    size_t szB   = (size_t)512 * sizeof(int);
    size_t szCsr = (size_t)NE * sizeof(int2);                  // 25.6 MB
    size_t need  = 2 * szT + szCnt + szOff + szB + szCsr;

    char* p = (char*)d_ws;
    float* T0 = (float*)p;          p += szT;
    float* T1 = (float*)p;          p += szT;

    if (ws_size >= need) {
        int*  cnt  = (int*)p;       p += szCnt;   // also reused as cursor
        int*  offv = (int*)p;       p += szOff;
        int*  bsum = (int*)p;       p += szB;
        int2* csr  = (int2*)p;      p += szCsr;

        // ---- build CSR by dst (once; reused by all 3 layers) ----
        hipMemsetAsync(cnt, 0, szCnt, stream);
        k_hist<<<gE, blk, 0, stream>>>(dst, cnt);
        k_breduce<<<SCAN_NBLK, blk, 0, stream>>>(cnt, bsum);
        k_bscan<<<SCAN_NBLK, blk, 0, stream>>>(cnt, bsum, offv);
        hipMemcpyAsync(cnt, offv, szCnt, hipMemcpyDeviceToDevice, stream);  // cursor
        k_build<<<gE, blk, 0, stream>>>(src, dst, ew, cnt, csr);

        // ---- layers (agg writes in-place target, node updates in-place) ----
        k_in_gemm<<<gN, blk, 0, stream>>>(x, W1a, T0);

        k_agg<<<gQ, blk, 0, stream>>>(offv, csr, T0, T1);
        k_node<false><<<gN, blk, 0, stream>>>(T1, b1a, W1b, b1b, W2a, T1);

        k_agg<<<gQ, blk, 0, stream>>>(offv, csr, T1, T0);
        k_node<false><<<gN, blk, 0, stream>>>(T0, b2a, W2b, b2b, W3a, T0);

        k_agg<<<gQ, blk, 0, stream>>>(offv, csr, T0, T1);
        k_node<true><<<gN, blk, 0, stream>>>(T1, b3a, W3b, b3b, nullptr, T1);

        k_pool<<<NG, blk, 0, stream>>>(T1, bat, Wlin, blin, (float*)d_out);
    } else {
        // fallback: atomic scatter path (T0 = messages, T1 = agg)
        k_in_gemm<<<gN, blk, 0, stream>>>(x, W1a, T0);
        hipMemsetAsync(T1, 0, szT, stream);
        k_scatter<<<gE, blk, 0, stream>>>(src, dst, ew, T0, T1);
        k_node<false><<<gN, blk, 0, stream>>>(T1, b1a, W1b, b1b, W2a, T0);
        hipMemsetAsync(T1, 0, szT, stream);
        k_scatter<<<gE, blk, 0, stream>>>(src, dst, ew, T0, T1);
        k_node<false><<<gN, blk, 0, stream>>>(T1, b2a, W2b, b2b, W3a, T0);
        hipMemsetAsync(T1, 0, szT, stream);
        k_scatter<<<gE, blk, 0, stream>>>(src, dst, ew, T0, T1);
        k_node<true><<<gN, blk, 0, stream>>>(T1, b3a, W3b, b3b, nullptr, T0);
        k_pool<<<NG, blk, 0, stream>>>(T0, bat, Wlin, blin, (float*)d_out);
    }
}

// Round 3
// 358.060 us; speedup vs baseline: 27.6052x; 1.8137x over previous
//
#include <hip/hip_runtime.h>
#include <math.h>

#define NN 100000
#define NE 3200000
#define FIN 64
#define HID 20
#define NG 128
#define NC 10

// ---- two-level counting-sort params ----
#define BSH 8                 // nodes per bucket = 256
#define NB1 391               // ceil(NN / 256)
#define NB1P 392
#define NBLK1 1024
#define E1 (NE / NBLK1)       // 3125 exactly

#define SCAN_ELEMS 1024
#define SCAN_NBLK ((NN + SCAN_ELEMS - 1) / SCAN_ELEMS)  // 98 (legacy path)

// ---------------- t = x @ W1a  (100000x64 @ 64x20) ----------------
__global__ __launch_bounds__(256) void k_in_gemm(const float* __restrict__ x,
                                                 const float* __restrict__ W,
                                                 float* __restrict__ t) {
    __shared__ float sW[FIN * HID];
    for (int i = threadIdx.x; i < FIN * HID; i += blockDim.x) sW[i] = W[i];
    __syncthreads();
    int node = blockIdx.x * blockDim.x + threadIdx.x;
    if (node >= NN) return;
    float acc[HID];
#pragma unroll
    for (int f = 0; f < HID; ++f) acc[f] = 0.f;
    const float4* xr = (const float4*)(x + node * FIN);
#pragma unroll 4
    for (int q = 0; q < FIN / 4; ++q) {
        float4 xv = xr[q];
        int k = q * 4;
#pragma unroll
        for (int f = 0; f < HID; ++f) acc[f] += xv.x * sW[(k + 0) * HID + f];
#pragma unroll
        for (int f = 0; f < HID; ++f) acc[f] += xv.y * sW[(k + 1) * HID + f];
#pragma unroll
        for (int f = 0; f < HID; ++f) acc[f] += xv.z * sW[(k + 2) * HID + f];
#pragma unroll
        for (int f = 0; f < HID; ++f) acc[f] += xv.w * sW[(k + 3) * HID + f];
    }
    float4* tr = (float4*)(t + node * HID);
#pragma unroll
    for (int q = 0; q < HID / 4; ++q) {
        float4 v;
        v.x = acc[q * 4 + 0]; v.y = acc[q * 4 + 1];
        v.z = acc[q * 4 + 2]; v.w = acc[q * 4 + 3];
        tr[q] = v;
    }
}

// ================= radix CSR build (no global data atomics) =================
// pass 1a: per-block coarse histogram -> ghist[bin * NBLK1 + blk]
__global__ __launch_bounds__(256) void k_p1count(const int* __restrict__ dst,
                                                 int* __restrict__ ghist) {
    __shared__ int h[NB1];
    for (int i = threadIdx.x; i < NB1; i += 256) h[i] = 0;
    __syncthreads();
    int base = blockIdx.x * E1;
    for (int i = threadIdx.x; i < E1; i += 256)
        atomicAdd(&h[dst[base + i] >> BSH], 1);
    __syncthreads();
    for (int b = threadIdx.x; b < NB1; b += 256)
        ghist[b * NBLK1 + blockIdx.x] = h[b];
}

// pass 1b: bucket totals
__global__ __launch_bounds__(256) void k_breduceB(const int* __restrict__ ghist,
                                                  int* __restrict__ bsum) {
    int bin = blockIdx.x;
    int s = 0;
    for (int i = threadIdx.x; i < NBLK1; i += 256) s += ghist[bin * NBLK1 + i];
    __shared__ int r[256];
    r[threadIdx.x] = s;
    __syncthreads();
    for (int o = 128; o > 0; o >>= 1) {
        if (threadIdx.x < o) r[threadIdx.x] += r[threadIdx.x + o];
        __syncthreads();
    }
    if (threadIdx.x == 0) bsum[bin] = r[0];
}

// pass 1c: exclusive scan of bucket totals -> bstart
__global__ __launch_bounds__(256) void k_bscanB(const int* __restrict__ bsum,
                                                int* __restrict__ bstart) {
    __shared__ int s[NB1];
    for (int i = threadIdx.x; i < NB1; i += 256) s[i] = bsum[i];
    __syncthreads();
    if (threadIdx.x == 0) {
        int acc = 0;
        for (int i = 0; i < NB1; ++i) { int v = s[i]; s[i] = acc; acc += v; }
    }
    __syncthreads();
    for (int i = threadIdx.x; i < NB1; i += 256) bstart[i] = s[i];
    if (threadIdx.x == 0) bstart[NB1] = NE;
}

// pass 1d: per-(block,bucket) base = bstart[bin] + prefix over blocks
__global__ __launch_bounds__(256) void k_bbase(const int* __restrict__ ghist,
                                               const int* __restrict__ bstart,
                                               int* __restrict__ gbase) {
    int bin = blockIdx.x;
    int t = threadIdx.x;
    int v[4];
    int s = 0;
    int base = bin * NBLK1 + t * 4;
#pragma unroll
    for (int k = 0; k < 4; ++k) { v[k] = ghist[base + k]; s += v[k]; }
    __shared__ int tsum[256];
    tsum[t] = s;
    __syncthreads();
    for (int d = 1; d < 256; d <<= 1) {
        int add = (t >= d) ? tsum[t - d] : 0;
        __syncthreads();
        tsum[t] += add;
        __syncthreads();
    }
    int excl = tsum[t] - s + bstart[bin];
#pragma unroll
    for (int k = 0; k < 4; ++k) {
        gbase[(size_t)(t * 4 + k) * NB1P + bin] = excl;  // [blk][bin] layout
        excl += v[k];
    }
}

// pass 1e: ranked coarse scatter via LDS cursors; pack (src | dlow<<17, w)
__global__ __launch_bounds__(256) void k_p1scatter(const int* __restrict__ src,
                                                   const int* __restrict__ dst,
                                                   const float* __restrict__ w,
                                                   const int* __restrict__ gbase,
                                                   int2* __restrict__ part) {
    __shared__ int cur[NB1];
    int t = threadIdx.x;
    for (int b = t; b < NB1; b += 256) cur[b] = gbase[(size_t)blockIdx.x * NB1P + b];
    __syncthreads();
    int base = blockIdx.x * E1;
    for (int i = t; i < E1; i += 256) {
        int e = base + i;
        int d = dst[e];
        int b = d >> BSH;
        int pos = atomicAdd(&cur[b], 1);
        part[pos] = make_int2(src[e] | ((d & 255) << 17), __float_as_int(w[e]));
    }
}

// pass 2: per-bucket counting sort -> exact CSR + off[]
__global__ __launch_bounds__(256) void k_p2(const int2* __restrict__ part,
                                            const int* __restrict__ bstart,
                                            int2* __restrict__ csr,
                                            int* __restrict__ off) {
    int b = blockIdx.x;
    int lo = bstart[b], hi = bstart[b + 1];
    int t = threadIdx.x;
    __shared__ int hist[256];
    hist[t] = 0;
    __syncthreads();
    for (int i = lo + t; i < hi; i += 256)
        atomicAdd(&hist[part[i].x >> 17], 1);
    __syncthreads();
    int a = hist[t];
    __shared__ int tsum[256];
    tsum[t] = a;
    __syncthreads();
    for (int d = 1; d < 256; d <<= 1) {
        int add = (t >= d) ? tsum[t - d] : 0;
        __syncthreads();
        tsum[t] += add;
        __syncthreads();
    }
    int excl = tsum[t] - a;
    __shared__ int cur[256];
    cur[t] = lo + excl;
    int node = (b << BSH) + t;
    if (node < NN) off[node] = lo + excl;
    if (b == NB1 - 1 && t == 0) off[NN] = NE;
    __syncthreads();
    for (int i = lo + t; i < hi; i += 256) {
        int2 pr = part[i];
        int ld = pr.x >> 17;
        int pos = atomicAdd(&cur[ld], 1);
        csr[pos] = make_int2(pr.x & 0x1FFFF, pr.y);
    }
}

// ================= legacy CSR build (middle fallback) =================
__global__ __launch_bounds__(256) void k_hist(const int* __restrict__ dst,
                                              int* __restrict__ cnt) {
    int e = blockIdx.x * blockDim.x + threadIdx.x;
    if (e >= NE) return;
    atomicAdd(&cnt[dst[e]], 1);
}

__global__ __launch_bounds__(256) void k_breduce(const int* __restrict__ cnt,
                                                 int* __restrict__ bsum) {
    int b = blockIdx.x;
    int t = threadIdx.x;
    int base = b * SCAN_ELEMS;
    int s = 0;
    for (int i = t; i < SCAN_ELEMS; i += 256) {
        int idx = base + i;
        if (idx < NN) s += cnt[idx];
    }
    __shared__ int red[256];
    red[t] = s;
    __syncthreads();
    for (int off = 128; off > 0; off >>= 1) {
        if (t < off) red[t] += red[t + off];
        __syncthreads();
    }
    if (t == 0) bsum[b] = red[0];
}

__global__ __launch_bounds__(256) void k_bscan(const int* __restrict__ cnt,
                                               const int* __restrict__ bsum,
                                               int* __restrict__ off) {
    int b = blockIdx.x, t = threadIdx.x;
    __shared__ int s_base;
    if (t == 0) {
        int s = 0;
        for (int j = 0; j < b; ++j) s += bsum[j];
        s_base = s;
    }
    __shared__ int tsum[256];
    int base_i = b * SCAN_ELEMS + t * 4;
    int v[4];
    int s = 0;
#pragma unroll
    for (int k = 0; k < 4; ++k) {
        int idx = base_i + k;
        v[k] = (idx < NN) ? cnt[idx] : 0;
        s += v[k];
    }
    tsum[t] = s;
    __syncthreads();
    for (int d = 1; d < 256; d <<= 1) {
        int add = (t >= d) ? tsum[t - d] : 0;
        __syncthreads();
        tsum[t] += add;
        __syncthreads();
    }
    int excl = tsum[t] - s + s_base;
#pragma unroll
    for (int k = 0; k < 4; ++k) {
        int idx = base_i + k;
        if (idx < NN) off[idx] = excl;
        excl += v[k];
    }
    if (b == 0 && t == 0) off[NN] = NE;
}

__global__ __launch_bounds__(256) void k_build(const int* __restrict__ src,
                                               const int* __restrict__ dst,
                                               const float* __restrict__ w,
                                               int* __restrict__ cursor,
                                               int2* __restrict__ csr) {
    int e = blockIdx.x * blockDim.x + threadIdx.x;
    if (e >= NE) return;
    int d = dst[e];
    int pos = atomicAdd(&cursor[d], 1);
    csr[pos] = make_int2(src[e], __float_as_int(w[e]));
}

// ---------------- Aggregation: 4 lanes per node, no atomics ----------------
__global__ __launch_bounds__(256) void k_agg(const int* __restrict__ off,
                                             const int2* __restrict__ csr,
                                             const float* __restrict__ t,
                                             float* __restrict__ agg) {
    int tid = blockIdx.x * blockDim.x + threadIdx.x;
    int node = tid >> 2;
    int j = tid & 3;
    if (node >= NN) return;
    int lo = off[node], hi = off[node + 1];
    float acc[HID];
#pragma unroll
    for (int f = 0; f < HID; ++f) acc[f] = 0.f;
    for (int i = lo + j; i < hi; i += 4) {
        int2 pr = csr[i];
        int s = pr.x;
        float wt = __int_as_float(pr.y);
        const float4* tr = (const float4*)(t + (long)s * HID);
#pragma unroll
        for (int q = 0; q < HID / 4; ++q) {
            float4 v = tr[q];
            acc[q * 4 + 0] += wt * v.x;
            acc[q * 4 + 1] += wt * v.y;
            acc[q * 4 + 2] += wt * v.z;
            acc[q * 4 + 3] += wt * v.w;
        }
    }
#pragma unroll
    for (int f = 0; f < HID; ++f) {
        acc[f] += __shfl_xor(acc[f], 1);
        acc[f] += __shfl_xor(acc[f], 2);
    }
    float* ar = agg + (long)node * HID + j * 5;
#pragma unroll
    for (int k = 0; k < 5; ++k) ar[k] = acc[j * 5 + k];
}

// ---------------- Node update (may run in-place: out == agg) ----------------
template <bool LAST>
__global__ __launch_bounds__(256) void k_node(const float* agg,
                                              const float* __restrict__ ba,
                                              const float* __restrict__ Wb,
                                              const float* __restrict__ bb,
                                              const float* __restrict__ Wnext,
                                              float* out) {
    __shared__ float sWb[HID * HID];
    __shared__ float sWn[HID * HID];
    __shared__ float sba[HID], sbb[HID];
    for (int i = threadIdx.x; i < HID * HID; i += blockDim.x) {
        sWb[i] = Wb[i];
        if (!LAST) sWn[i] = Wnext[i];
    }
    if (threadIdx.x < HID) {
        sba[threadIdx.x] = ba[threadIdx.x];
        sbb[threadIdx.x] = bb[threadIdx.x];
    }
    __syncthreads();
    int node = blockIdx.x * blockDim.x + threadIdx.x;
    if (node >= NN) return;

    float z1[HID];
    const float4* ar = (const float4*)(agg + (long)node * HID);
#pragma unroll
    for (int q = 0; q < HID / 4; ++q) {
        float4 v = ar[q];
        z1[q * 4 + 0] = v.x; z1[q * 4 + 1] = v.y;
        z1[q * 4 + 2] = v.z; z1[q * 4 + 3] = v.w;
    }
#pragma unroll
    for (int f = 0; f < HID; ++f) z1[f] = fmaxf(z1[f] + sba[f], 0.f);

    float z2[HID];
#pragma unroll
    for (int fo = 0; fo < HID; ++fo) {
        float a = sbb[fo];
#pragma unroll
        for (int k = 0; k < HID; ++k) a += z1[k] * sWb[k * HID + fo];
        z2[fo] = fmaxf(a, 0.f);
    }

    float ss = 0.f;
#pragma unroll
    for (int f = 0; f < HID; ++f) ss += z2[f] * z2[f];
    float scale = 1.f / fmaxf(sqrtf(ss), 1e-12f);
#pragma unroll
    for (int f = 0; f < HID; ++f) z2[f] *= scale;

    float res[HID];
    if (LAST) {
#pragma unroll
        for (int f = 0; f < HID; ++f) res[f] = z2[f];
    } else {
#pragma unroll
        for (int fo = 0; fo < HID; ++fo) {
            float a = 0.f;
#pragma unroll
            for (int k = 0; k < HID; ++k) a += z2[k] * sWn[k * HID + fo];
            res[fo] = a;
        }
    }
    float4* orow = (float4*)(out + (long)node * HID);
#pragma unroll
    for (int q = 0; q < HID / 4; ++q) {
        float4 v;
        v.x = res[q * 4 + 0]; v.y = res[q * 4 + 1];
        v.z = res[q * 4 + 2]; v.w = res[q * 4 + 3];
        orow[q] = v;
    }
}

// ---------------- Fallback atomic scatter (if ws too small) ----------------
__global__ __launch_bounds__(256) void k_scatter(const int* __restrict__ src,
                                                 const int* __restrict__ dst,
                                                 const float* __restrict__ w,
                                                 const float* __restrict__ t,
                                                 float* __restrict__ agg) {
    int e = blockIdx.x * blockDim.x + threadIdx.x;
    if (e >= NE) return;
    int s = src[e];
    int d = dst[e];
    float wt = w[e];
    const float4* tr = (const float4*)(t + (long)s * HID);
    float* ar = agg + (long)d * HID;
#pragma unroll
    for (int q = 0; q < HID / 4; ++q) {
        float4 v = tr[q];
        atomicAdd(ar + q * 4 + 0, v.x * wt);
        atomicAdd(ar + q * 4 + 1, v.y * wt);
        atomicAdd(ar + q * 4 + 2, v.z * wt);
        atomicAdd(ar + q * 4 + 3, v.w * wt);
    }
}

// ---------------- Pooling + head ----------------
__global__ __launch_bounds__(256) void k_pool(const float* __restrict__ h,
                                              const int* __restrict__ batch,
                                              const float* __restrict__ Wlin,
                                              const float* __restrict__ blin,
                                              float* __restrict__ out) {
    int g = blockIdx.x;
    __shared__ int s_lo, s_hi;
    if (threadIdx.x == 0) {
        int a = 0, b = NN;
        while (a < b) { int m = (a + b) >> 1; if (batch[m] < g) a = m + 1; else b = m; }
        s_lo = a;
        b = NN;
        while (a < b) { int m = (a + b) >> 1; if (batch[m] < g + 1) a = m + 1; else b = m; }
        s_hi = a;
    }
    __syncthreads();
    int lo = s_lo, hi = s_hi;

    float sm[HID], mx[HID];
#pragma unroll
    for (int f = 0; f < HID; ++f) { sm[f] = 0.f; mx[f] = 0.f; }

    for (int i = lo + threadIdx.x; i < hi; i += blockDim.x) {
        const float4* hr = (const float4*)(h + (long)i * HID);
#pragma unroll
        for (int q = 0; q < HID / 4; ++q) {
            float4 v = hr[q];
            sm[q * 4 + 0] += v.x; mx[q * 4 + 0] = fmaxf(mx[q * 4 + 0], v.x);
            sm[q * 4 + 1] += v.y; mx[q * 4 + 1] = fmaxf(mx[q * 4 + 1], v.y);
            sm[q * 4 + 2] += v.z; mx[q * 4 + 2] = fmaxf(mx[q * 4 + 2], v.z);
            sm[q * 4 + 3] += v.w; mx[q * 4 + 3] = fmaxf(mx[q * 4 + 3], v.w);
        }
    }

#pragma unroll
    for (int f = 0; f < HID; ++f) {
        float s = sm[f], m = mx[f];
        for (int off = 32; off > 0; off >>= 1) {
            s += __shfl_down(s, off);
            m = fmaxf(m, __shfl_down(m, off));
        }
        sm[f] = s; mx[f] = m;
    }

    __shared__ float psum[4][HID], pmax[4][HID];
    int wave = threadIdx.x >> 6;
    int lane = threadIdx.x & 63;
    if (lane == 0) {
#pragma unroll
        for (int f = 0; f < HID; ++f) { psum[wave][f] = sm[f]; pmax[wave][f] = mx[f]; }
    }
    __syncthreads();

    __shared__ float fsum[HID], fmax_[HID];
    if (threadIdx.x < HID) {
        int f = threadIdx.x;
        fsum[f] = psum[0][f] + psum[1][f] + psum[2][f] + psum[3][f];
        fmax_[f] = fmaxf(fmaxf(pmax[0][f], pmax[1][f]), fmaxf(pmax[2][f], pmax[3][f]));
    }
    __syncthreads();

    if (threadIdx.x < NC) {
        int c = threadIdx.x;
        float cnt = (float)(hi - lo);
        float inv = 1.f / fmaxf(cnt, 1.f);
        float o = blin[c];
#pragma unroll
        for (int f = 0; f < HID; ++f) {
            o += fmax_[f] * Wlin[f * NC + c];
            o += (fsum[f] * inv) * Wlin[(HID + f) * NC + c];
        }
        out[g * NC + c] = o;
    }
}

extern "C" void kernel_launch(void* const* d_in, const int* in_sizes, int n_in,
                              void* d_out, int out_size, void* d_ws, size_t ws_size,
                              hipStream_t stream) {
    const float* x   = (const float*)d_in[0];
    const int*   ei  = (const int*)d_in[1];
    const int*   bat = (const int*)d_in[2];
    const float* ew  = (const float*)d_in[3];
    const float* W1a = (const float*)d_in[4];
    const float* b1a = (const float*)d_in[5];
    const float* W1b = (const float*)d_in[6];
    const float* b1b = (const float*)d_in[7];
    const float* W2a = (const float*)d_in[8];
    const float* b2a = (const float*)d_in[9];
    const float* W2b = (const float*)d_in[10];
    const float* b2b = (const float*)d_in[11];
    const float* W3a = (const float*)d_in[12];
    const float* b3a = (const float*)d_in[13];
    const float* W3b = (const float*)d_in[14];
    const float* b3b = (const float*)d_in[15];
    const float* Wlin = (const float*)d_in[16];
    const float* blin = (const float*)d_in[17];

    const int* src = ei;
    const int* dst = ei + NE;

    dim3 blk(256);
    dim3 gN((NN + 255) / 256);
    dim3 gE((NE + 255) / 256);
    dim3 gQ(((size_t)NN * 4 + 255) / 256);

    size_t szT    = (size_t)NN * HID * sizeof(float);         // 8 MB
    size_t szCsr  = (size_t)NE * sizeof(int2);                // 25.6 MB
    size_t szOff  = ((size_t)(NN + 1) * sizeof(int) + 15) & ~(size_t)15;
    size_t szGh   = (size_t)NB1 * NBLK1 * sizeof(int);        // 1.6 MB
    size_t szGb   = (size_t)NBLK1 * NB1P * sizeof(int);       // 1.6 MB
    size_t szSm   = 2048;
    size_t szPart = szCsr > 2 * szT ? szCsr : 2 * szT;        // part ∪ (T0,T1)
    size_t need_radix = szCsr + szOff + szGh + szGb + 2 * szSm + szPart;

    size_t szCnt = (size_t)NN * sizeof(int);
    size_t need_old = 2 * szT + szCnt + szOff + 2048 + szCsr;

    if (ws_size >= need_radix) {
        char* p = (char*)d_ws;
        int2* csr    = (int2*)p;  p += szCsr;
        int*  offv   = (int*)p;   p += szOff;
        int*  ghist  = (int*)p;   p += szGh;
        int*  gbase  = (int*)p;   p += szGb;
        int*  bsum   = (int*)p;   p += szSm;
        int*  bstart = (int*)p;   p += szSm;
        int2* part   = (int2*)p;             // dead after k_p2; then hosts T0,T1
        float* T0 = (float*)part;
        float* T1 = T0 + (size_t)NN * HID;

        // ---- build CSR (two-level counting sort, once; reused by 3 layers) ----
        k_p1count<<<NBLK1, blk, 0, stream>>>(dst, ghist);
        k_breduceB<<<NB1, blk, 0, stream>>>(ghist, bsum);
        k_bscanB<<<1, blk, 0, stream>>>(bsum, bstart);
        k_bbase<<<NB1, blk, 0, stream>>>(ghist, bstart, gbase);
        k_p1scatter<<<NBLK1, blk, 0, stream>>>(src, dst, ew, gbase, part);
        k_p2<<<NB1, blk, 0, stream>>>(part, bstart, csr, offv);

        // ---- layers ----
        k_in_gemm<<<gN, blk, 0, stream>>>(x, W1a, T0);

        k_agg<<<gQ, blk, 0, stream>>>(offv, csr, T0, T1);
        k_node<false><<<gN, blk, 0, stream>>>(T1, b1a, W1b, b1b, W2a, T1);

        k_agg<<<gQ, blk, 0, stream>>>(offv, csr, T1, T0);
        k_node<false><<<gN, blk, 0, stream>>>(T0, b2a, W2b, b2b, W3a, T0);

        k_agg<<<gQ, blk, 0, stream>>>(offv, csr, T0, T1);
        k_node<true><<<gN, blk, 0, stream>>>(T1, b3a, W3b, b3b, nullptr, T1);

        k_pool<<<NG, blk, 0, stream>>>(T1, bat, Wlin, blin, (float*)d_out);
    } else if (ws_size >= need_old) {
        char* p = (char*)d_ws;
        float* T0 = (float*)p;  p += szT;
        float* T1 = (float*)p;  p += szT;
        int*  cnt  = (int*)p;   p += szCnt;
        int*  offv = (int*)p;   p += szOff;
        int*  bsum = (int*)p;   p += 2048;
        int2* csr  = (int2*)p;

        hipMemsetAsync(cnt, 0, szCnt, stream);
        k_hist<<<gE, blk, 0, stream>>>(dst, cnt);
        k_breduce<<<SCAN_NBLK, blk, 0, stream>>>(cnt, bsum);
        k_bscan<<<SCAN_NBLK, blk, 0, stream>>>(cnt, bsum, offv);
        hipMemcpyAsync(cnt, offv, szCnt, hipMemcpyDeviceToDevice, stream);
        k_build<<<gE, blk, 0, stream>>>(src, dst, ew, cnt, csr);

        k_in_gemm<<<gN, blk, 0, stream>>>(x, W1a, T0);
        k_agg<<<gQ, blk, 0, stream>>>(offv, csr, T0, T1);
        k_node<false><<<gN, blk, 0, stream>>>(T1, b1a, W1b, b1b, W2a, T1);
        k_agg<<<gQ, blk, 0, stream>>>(offv, csr, T1, T0);
        k_node<false><<<gN, blk, 0, stream>>>(T0, b2a, W2b, b2b, W3a, T0);
        k_agg<<<gQ, blk, 0, stream>>>(offv, csr, T0, T1);
        k_node<true><<<gN, blk, 0, stream>>>(T1, b3a, W3b, b3b, nullptr, T1);
        k_pool<<<NG, blk, 0, stream>>>(T1, bat, Wlin, blin, (float*)d_out);
    } else {
        char* p = (char*)d_ws;
        float* T0 = (float*)p;  p += szT;
        float* T1 = (float*)p;

        k_in_gemm<<<gN, blk, 0, stream>>>(x, W1a, T0);
        hipMemsetAsync(T1, 0, szT, stream);
        k_scatter<<<gE, blk, 0, stream>>>(src, dst, ew, T0, T1);
        k_node<false><<<gN, blk, 0, stream>>>(T1, b1a, W1b, b1b, W2a, T0);
        hipMemsetAsync(T1, 0, szT, stream);
        k_scatter<<<gE, blk, 0, stream>>>(src, dst, ew, T0, T1);
        k_node<false><<<gN, blk, 0, stream>>>(T1, b2a, W2b, b2b, W3a, T0);
        hipMemsetAsync(T1, 0, szT, stream);
        k_scatter<<<gE, blk, 0, stream>>>(src, dst, ew, T0, T1);
        k_node<true><<<gN, blk, 0, stream>>>(T1, b3a, W3b, b3b, nullptr, T0);
        k_pool<<<NG, blk, 0, stream>>>(T0, bat, Wlin, blin, (float*)d_out);
    }
}

// Round 4
// 304.745 us; speedup vs baseline: 32.4347x; 1.1749x over previous
//
#include <hip/hip_runtime.h>
#include <hip/hip_fp16.h>
#include <math.h>

#define NN 100000
#define NE 3200000
#define FIN 64
#define HID 20
#define NG 128
#define NC 10

// ---- two-level counting-sort params ----
#define BSH 8                 // nodes per bucket = 256
#define NB1 391               // ceil(NN / 256)
#define NB1P 392
#define NBLK1 1024
#define E1 (NE / NBLK1)       // 3125 exactly

// ---------------- t0 = x @ W1a, stored f16  ----------------
__global__ __launch_bounds__(256) void k_in_gemm_h(const float* __restrict__ x,
                                                   const float* __restrict__ W,
                                                   __half* __restrict__ t) {
    __shared__ float sW[FIN * HID];
    for (int i = threadIdx.x; i < FIN * HID; i += blockDim.x) sW[i] = W[i];
    __syncthreads();
    int node = blockIdx.x * blockDim.x + threadIdx.x;
    if (node >= NN) return;
    float acc[HID];
#pragma unroll
    for (int f = 0; f < HID; ++f) acc[f] = 0.f;
    const float4* xr = (const float4*)(x + node * FIN);
#pragma unroll 4
    for (int q = 0; q < FIN / 4; ++q) {
        float4 xv = xr[q];
        int k = q * 4;
#pragma unroll
        for (int f = 0; f < HID; ++f) acc[f] += xv.x * sW[(k + 0) * HID + f];
#pragma unroll
        for (int f = 0; f < HID; ++f) acc[f] += xv.y * sW[(k + 1) * HID + f];
#pragma unroll
        for (int f = 0; f < HID; ++f) acc[f] += xv.z * sW[(k + 2) * HID + f];
#pragma unroll
        for (int f = 0; f < HID; ++f) acc[f] += xv.w * sW[(k + 3) * HID + f];
    }
    uint32_t* orow = (uint32_t*)t + (size_t)node * (HID / 2);
#pragma unroll
    for (int m = 0; m < HID / 2; ++m) {
        __half2 hh = __floats2half2_rn(acc[2 * m], acc[2 * m + 1]);
        orow[m] = *reinterpret_cast<uint32_t*>(&hh);
    }
}

// ================= radix CSR build (no global data atomics) =================
__global__ __launch_bounds__(256) void k_p1count(const int* __restrict__ dst,
                                                 int* __restrict__ ghist) {
    __shared__ int h[NB1];
    for (int i = threadIdx.x; i < NB1; i += 256) h[i] = 0;
    __syncthreads();
    int base = blockIdx.x * E1;
    for (int i = threadIdx.x; i < E1; i += 256)
        atomicAdd(&h[dst[base + i] >> BSH], 1);
    __syncthreads();
    for (int b = threadIdx.x; b < NB1; b += 256)
        ghist[b * NBLK1 + blockIdx.x] = h[b];
}

__global__ __launch_bounds__(256) void k_breduceB(const int* __restrict__ ghist,
                                                  int* __restrict__ bsum) {
    int bin = blockIdx.x;
    int s = 0;
    for (int i = threadIdx.x; i < NBLK1; i += 256) s += ghist[bin * NBLK1 + i];
    __shared__ int r[256];
    r[threadIdx.x] = s;
    __syncthreads();
    for (int o = 128; o > 0; o >>= 1) {
        if (threadIdx.x < o) r[threadIdx.x] += r[threadIdx.x + o];
        __syncthreads();
    }
    if (threadIdx.x == 0) bsum[bin] = r[0];
}

__global__ __launch_bounds__(256) void k_bscanB(const int* __restrict__ bsum,
                                                int* __restrict__ bstart) {
    __shared__ int s[NB1];
    for (int i = threadIdx.x; i < NB1; i += 256) s[i] = bsum[i];
    __syncthreads();
    if (threadIdx.x == 0) {
        int acc = 0;
        for (int i = 0; i < NB1; ++i) { int v = s[i]; s[i] = acc; acc += v; }
    }
    __syncthreads();
    for (int i = threadIdx.x; i < NB1; i += 256) bstart[i] = s[i];
    if (threadIdx.x == 0) bstart[NB1] = NE;
}

__global__ __launch_bounds__(256) void k_bbase(const int* __restrict__ ghist,
                                               const int* __restrict__ bstart,
                                               int* __restrict__ gbase) {
    int bin = blockIdx.x;
    int t = threadIdx.x;
    int v[4];
    int s = 0;
    int base = bin * NBLK1 + t * 4;
#pragma unroll
    for (int k = 0; k < 4; ++k) { v[k] = ghist[base + k]; s += v[k]; }
    __shared__ int tsum[256];
    tsum[t] = s;
    __syncthreads();
    for (int d = 1; d < 256; d <<= 1) {
        int add = (t >= d) ? tsum[t - d] : 0;
        __syncthreads();
        tsum[t] += add;
        __syncthreads();
    }
    int excl = tsum[t] - s + bstart[bin];
#pragma unroll
    for (int k = 0; k < 4; ++k) {
        gbase[(size_t)(t * 4 + k) * NB1P + bin] = excl;
        excl += v[k];
    }
}

__global__ __launch_bounds__(256) void k_p1scatter(const int* __restrict__ src,
                                                   const int* __restrict__ dst,
                                                   const float* __restrict__ w,
                                                   const int* __restrict__ gbase,
                                                   int2* __restrict__ part) {
    __shared__ int cur[NB1];
    int t = threadIdx.x;
    for (int b = t; b < NB1; b += 256) cur[b] = gbase[(size_t)blockIdx.x * NB1P + b];
    __syncthreads();
    int base = blockIdx.x * E1;
    for (int i = t; i < E1; i += 256) {
        int e = base + i;
        int d = dst[e];
        int b = d >> BSH;
        int pos = atomicAdd(&cur[b], 1);
        part[pos] = make_int2(src[e] | ((d & 255) << 17), __float_as_int(w[e]));
    }
}

__global__ __launch_bounds__(256) void k_p2(const int2* __restrict__ part,
                                            const int* __restrict__ bstart,
                                            int2* __restrict__ csr,
                                            int* __restrict__ off) {
    int b = blockIdx.x;
    int lo = bstart[b], hi = bstart[b + 1];
    int t = threadIdx.x;
    __shared__ int hist[256];
    hist[t] = 0;
    __syncthreads();
    for (int i = lo + t; i < hi; i += 256)
        atomicAdd(&hist[part[i].x >> 17], 1);
    __syncthreads();
    int a = hist[t];
    __shared__ int tsum[256];
    tsum[t] = a;
    __syncthreads();
    for (int d = 1; d < 256; d <<= 1) {
        int add = (t >= d) ? tsum[t - d] : 0;
        __syncthreads();
        tsum[t] += add;
        __syncthreads();
    }
    int excl = tsum[t] - a;
    __shared__ int cur[256];
    cur[t] = lo + excl;
    int node = (b << BSH) + t;
    if (node < NN) off[node] = lo + excl;
    if (b == NB1 - 1 && t == 0) off[NN] = NE;
    __syncthreads();
    for (int i = lo + t; i < hi; i += 256) {
        int2 pr = part[i];
        int ld = pr.x >> 17;
        int pos = atomicAdd(&cur[ld], 1);
        csr[pos] = make_int2(pr.x & 0x1FFFF, pr.y);
    }
}

// ---------------- Fused layer: gather(f16) + MLP + normalize + premult ----------------
// 4 lanes per node; after quad-reduce all lanes hold full agg vector;
// MLP computed redundantly; quad cooperatively writes the f16 output row.
template <bool LAST>
__global__ __launch_bounds__(256) void k_layer(const int* __restrict__ off,
                                               const int2* __restrict__ csr,
                                               const __half* __restrict__ tin,
                                               const float* __restrict__ ba,
                                               const float* __restrict__ Wb,
                                               const float* __restrict__ bb,
                                               const float* __restrict__ Wnext,
                                               __half* __restrict__ tout) {
    __shared__ float sWb[HID * HID];
    __shared__ float sWn[HID * HID];
    __shared__ float sba[HID], sbb[HID];
    for (int i = threadIdx.x; i < HID * HID; i += blockDim.x) {
        sWb[i] = Wb[i];
        if (!LAST) sWn[i] = Wnext[i];
    }
    if (threadIdx.x < HID) {
        sba[threadIdx.x] = ba[threadIdx.x];
        sbb[threadIdx.x] = bb[threadIdx.x];
    }
    __syncthreads();

    int tid = blockIdx.x * blockDim.x + threadIdx.x;
    int node = tid >> 2;
    int j = tid & 3;
    if (node >= NN) return;
    int lo = off[node], hi = off[node + 1];

    float acc[HID];
#pragma unroll
    for (int f = 0; f < HID; ++f) acc[f] = 0.f;

    for (int i = lo + j; i < hi; i += 4) {
        int2 pr = csr[i];
        float wt = __int_as_float(pr.y);
        const uint2* r = (const uint2*)tin + (size_t)pr.x * 5;
#pragma unroll
        for (int k = 0; k < 5; ++k) {
            uint2 u = r[k];
            __half2 h0 = *reinterpret_cast<const __half2*>(&u.x);
            __half2 h1 = *reinterpret_cast<const __half2*>(&u.y);
            float2 f0 = __half22float2(h0);
            float2 f1 = __half22float2(h1);
            acc[4 * k + 0] += wt * f0.x;
            acc[4 * k + 1] += wt * f0.y;
            acc[4 * k + 2] += wt * f1.x;
            acc[4 * k + 3] += wt * f1.y;
        }
    }
    // quad reduce -> every lane has the full 20-vector
#pragma unroll
    for (int f = 0; f < HID; ++f) {
        acc[f] += __shfl_xor(acc[f], 1);
        acc[f] += __shfl_xor(acc[f], 2);
    }

    // MLP (redundant across the 4 lanes)
    float z1[HID];
#pragma unroll
    for (int f = 0; f < HID; ++f) z1[f] = fmaxf(acc[f] + sba[f], 0.f);

    float z2[HID];
#pragma unroll
    for (int fo = 0; fo < HID; ++fo) {
        float a = sbb[fo];
#pragma unroll
        for (int k = 0; k < HID; ++k) a += z1[k] * sWb[k * HID + fo];
        z2[fo] = fmaxf(a, 0.f);
    }

    float ss = 0.f;
#pragma unroll
    for (int f = 0; f < HID; ++f) ss += z2[f] * z2[f];
    float scale = 1.f / fmaxf(sqrtf(ss), 1e-12f);
#pragma unroll
    for (int f = 0; f < HID; ++f) z2[f] *= scale;

    float res[HID];
    if (LAST) {
#pragma unroll
        for (int f = 0; f < HID; ++f) res[f] = z2[f];
    } else {
#pragma unroll
        for (int fo = 0; fo < HID; ++fo) {
            float a = 0.f;
#pragma unroll
            for (int k = 0; k < HID; ++k) a += z2[k] * sWn[k * HID + fo];
            res[fo] = a;
        }
    }

    // quad-cooperative f16 row write (10 uint32 words)
    uint32_t* orow = (uint32_t*)tout + (size_t)node * (HID / 2);
#pragma unroll
    for (int m0 = 0; m0 < 12; m0 += 4) {
        int m = m0 + j;
        if (m < HID / 2) {
            __half2 hh = __floats2half2_rn(res[2 * m], res[2 * m + 1]);
            orow[m] = *reinterpret_cast<uint32_t*>(&hh);
        }
    }
}

// ---------------- Pooling + head (f16 h) ----------------
__global__ __launch_bounds__(256) void k_pool_h(const __half* __restrict__ h,
                                                const int* __restrict__ batch,
                                                const float* __restrict__ Wlin,
                                                const float* __restrict__ blin,
                                                float* __restrict__ out) {
    int g = blockIdx.x;
    __shared__ int s_lo, s_hi;
    if (threadIdx.x == 0) {
        int a = 0, b = NN;
        while (a < b) { int m = (a + b) >> 1; if (batch[m] < g) a = m + 1; else b = m; }
        s_lo = a;
        b = NN;
        while (a < b) { int m = (a + b) >> 1; if (batch[m] < g + 1) a = m + 1; else b = m; }
        s_hi = a;
    }
    __syncthreads();
    int lo = s_lo, hi = s_hi;

    float sm[HID], mx[HID];
#pragma unroll
    for (int f = 0; f < HID; ++f) { sm[f] = 0.f; mx[f] = 0.f; }

    for (int i = lo + threadIdx.x; i < hi; i += blockDim.x) {
        const uint2* hr = (const uint2*)h + (size_t)i * 5;
#pragma unroll
        for (int k = 0; k < 5; ++k) {
            uint2 u = hr[k];
            __half2 h0 = *reinterpret_cast<const __half2*>(&u.x);
            __half2 h1 = *reinterpret_cast<const __half2*>(&u.y);
            float2 f0 = __half22float2(h0);
            float2 f1 = __half22float2(h1);
            sm[4 * k + 0] += f0.x; mx[4 * k + 0] = fmaxf(mx[4 * k + 0], f0.x);
            sm[4 * k + 1] += f0.y; mx[4 * k + 1] = fmaxf(mx[4 * k + 1], f0.y);
            sm[4 * k + 2] += f1.x; mx[4 * k + 2] = fmaxf(mx[4 * k + 2], f1.x);
            sm[4 * k + 3] += f1.y; mx[4 * k + 3] = fmaxf(mx[4 * k + 3], f1.y);
        }
    }

#pragma unroll
    for (int f = 0; f < HID; ++f) {
        float s = sm[f], m = mx[f];
        for (int off = 32; off > 0; off >>= 1) {
            s += __shfl_down(s, off);
            m = fmaxf(m, __shfl_down(m, off));
        }
        sm[f] = s; mx[f] = m;
    }

    __shared__ float psum[4][HID], pmax[4][HID];
    int wave = threadIdx.x >> 6;
    int lane = threadIdx.x & 63;
    if (lane == 0) {
#pragma unroll
        for (int f = 0; f < HID; ++f) { psum[wave][f] = sm[f]; pmax[wave][f] = mx[f]; }
    }
    __syncthreads();

    __shared__ float fsum[HID], fmax_[HID];
    if (threadIdx.x < HID) {
        int f = threadIdx.x;
        fsum[f] = psum[0][f] + psum[1][f] + psum[2][f] + psum[3][f];
        fmax_[f] = fmaxf(fmaxf(pmax[0][f], pmax[1][f]), fmaxf(pmax[2][f], pmax[3][f]));
    }
    __syncthreads();

    if (threadIdx.x < NC) {
        int c = threadIdx.x;
        float cnt = (float)(hi - lo);
        float inv = 1.f / fmaxf(cnt, 1.f);
        float o = blin[c];
#pragma unroll
        for (int f = 0; f < HID; ++f) {
            o += fmax_[f] * Wlin[f * NC + c];
            o += (fsum[f] * inv) * Wlin[(HID + f) * NC + c];
        }
        out[g * NC + c] = o;
    }
}

// ================= fp32 fallback path (ws too small) =================
__global__ __launch_bounds__(256) void k_in_gemm(const float* __restrict__ x,
                                                 const float* __restrict__ W,
                                                 float* __restrict__ t) {
    __shared__ float sW[FIN * HID];
    for (int i = threadIdx.x; i < FIN * HID; i += blockDim.x) sW[i] = W[i];
    __syncthreads();
    int node = blockIdx.x * blockDim.x + threadIdx.x;
    if (node >= NN) return;
    float acc[HID];
#pragma unroll
    for (int f = 0; f < HID; ++f) acc[f] = 0.f;
    const float4* xr = (const float4*)(x + node * FIN);
    for (int q = 0; q < FIN / 4; ++q) {
        float4 xv = xr[q];
        int k = q * 4;
#pragma unroll
        for (int f = 0; f < HID; ++f)
            acc[f] += xv.x * sW[k * HID + f] + xv.y * sW[(k + 1) * HID + f] +
                      xv.z * sW[(k + 2) * HID + f] + xv.w * sW[(k + 3) * HID + f];
    }
    float4* tr = (float4*)(t + node * HID);
#pragma unroll
    for (int q = 0; q < HID / 4; ++q) {
        float4 v;
        v.x = acc[q * 4 + 0]; v.y = acc[q * 4 + 1];
        v.z = acc[q * 4 + 2]; v.w = acc[q * 4 + 3];
        tr[q] = v;
    }
}

__global__ __launch_bounds__(256) void k_scatter(const int* __restrict__ src,
                                                 const int* __restrict__ dst,
                                                 const float* __restrict__ w,
                                                 const float* __restrict__ t,
                                                 float* __restrict__ agg) {
    int e = blockIdx.x * blockDim.x + threadIdx.x;
    if (e >= NE) return;
    int s = src[e];
    int d = dst[e];
    float wt = w[e];
    const float4* tr = (const float4*)(t + (long)s * HID);
    float* ar = agg + (long)d * HID;
#pragma unroll
    for (int q = 0; q < HID / 4; ++q) {
        float4 v = tr[q];
        atomicAdd(ar + q * 4 + 0, v.x * wt);
        atomicAdd(ar + q * 4 + 1, v.y * wt);
        atomicAdd(ar + q * 4 + 2, v.z * wt);
        atomicAdd(ar + q * 4 + 3, v.w * wt);
    }
}

template <bool LAST>
__global__ __launch_bounds__(256) void k_node(const float* agg,
                                              const float* __restrict__ ba,
                                              const float* __restrict__ Wb,
                                              const float* __restrict__ bb,
                                              const float* __restrict__ Wnext,
                                              float* out) {
    __shared__ float sWb[HID * HID];
    __shared__ float sWn[HID * HID];
    __shared__ float sba[HID], sbb[HID];
    for (int i = threadIdx.x; i < HID * HID; i += blockDim.x) {
        sWb[i] = Wb[i];
        if (!LAST) sWn[i] = Wnext[i];
    }
    if (threadIdx.x < HID) {
        sba[threadIdx.x] = ba[threadIdx.x];
        sbb[threadIdx.x] = bb[threadIdx.x];
    }
    __syncthreads();
    int node = blockIdx.x * blockDim.x + threadIdx.x;
    if (node >= NN) return;

    float z1[HID];
    const float4* ar = (const float4*)(agg + (long)node * HID);
#pragma unroll
    for (int q = 0; q < HID / 4; ++q) {
        float4 v = ar[q];
        z1[q * 4 + 0] = v.x; z1[q * 4 + 1] = v.y;
        z1[q * 4 + 2] = v.z; z1[q * 4 + 3] = v.w;
    }
#pragma unroll
    for (int f = 0; f < HID; ++f) z1[f] = fmaxf(z1[f] + sba[f], 0.f);

    float z2[HID];
#pragma unroll
    for (int fo = 0; fo < HID; ++fo) {
        float a = sbb[fo];
#pragma unroll
        for (int k = 0; k < HID; ++k) a += z1[k] * sWb[k * HID + fo];
        z2[fo] = fmaxf(a, 0.f);
    }
    float ss = 0.f;
#pragma unroll
    for (int f = 0; f < HID; ++f) ss += z2[f] * z2[f];
    float scale = 1.f / fmaxf(sqrtf(ss), 1e-12f);
#pragma unroll
    for (int f = 0; f < HID; ++f) z2[f] *= scale;

    float res[HID];
    if (LAST) {
#pragma unroll
        for (int f = 0; f < HID; ++f) res[f] = z2[f];
    } else {
#pragma unroll
        for (int fo = 0; fo < HID; ++fo) {
            float a = 0.f;
#pragma unroll
            for (int k = 0; k < HID; ++k) a += z2[k] * sWn[k * HID + fo];
            res[fo] = a;
        }
    }
    float4* orow = (float4*)(out + (long)node * HID);
#pragma unroll
    for (int q = 0; q < HID / 4; ++q) {
        float4 v;
        v.x = res[q * 4 + 0]; v.y = res[q * 4 + 1];
        v.z = res[q * 4 + 2]; v.w = res[q * 4 + 3];
        orow[q] = v;
    }
}

__global__ __launch_bounds__(256) void k_pool(const float* __restrict__ h,
                                              const int* __restrict__ batch,
                                              const float* __restrict__ Wlin,
                                              const float* __restrict__ blin,
                                              float* __restrict__ out) {
    int g = blockIdx.x;
    __shared__ int s_lo, s_hi;
    if (threadIdx.x == 0) {
        int a = 0, b = NN;
        while (a < b) { int m = (a + b) >> 1; if (batch[m] < g) a = m + 1; else b = m; }
        s_lo = a;
        b = NN;
        while (a < b) { int m = (a + b) >> 1; if (batch[m] < g + 1) a = m + 1; else b = m; }
        s_hi = a;
    }
    __syncthreads();
    int lo = s_lo, hi = s_hi;
    float sm[HID], mx[HID];
#pragma unroll
    for (int f = 0; f < HID; ++f) { sm[f] = 0.f; mx[f] = 0.f; }
    for (int i = lo + threadIdx.x; i < hi; i += blockDim.x) {
        const float4* hr = (const float4*)(h + (long)i * HID);
#pragma unroll
        for (int q = 0; q < HID / 4; ++q) {
            float4 v = hr[q];
            sm[q * 4 + 0] += v.x; mx[q * 4 + 0] = fmaxf(mx[q * 4 + 0], v.x);
            sm[q * 4 + 1] += v.y; mx[q * 4 + 1] = fmaxf(mx[q * 4 + 1], v.y);
            sm[q * 4 + 2] += v.z; mx[q * 4 + 2] = fmaxf(mx[q * 4 + 2], v.z);
            sm[q * 4 + 3] += v.w; mx[q * 4 + 3] = fmaxf(mx[q * 4 + 3], v.w);
        }
    }
#pragma unroll
    for (int f = 0; f < HID; ++f) {
        float s = sm[f], m = mx[f];
        for (int off = 32; off > 0; off >>= 1) {
            s += __shfl_down(s, off);
            m = fmaxf(m, __shfl_down(m, off));
        }
        sm[f] = s; mx[f] = m;
    }
    __shared__ float psum[4][HID], pmax[4][HID];
    int wave = threadIdx.x >> 6;
    int lane = threadIdx.x & 63;
    if (lane == 0) {
#pragma unroll
        for (int f = 0; f < HID; ++f) { psum[wave][f] = sm[f]; pmax[wave][f] = mx[f]; }
    }
    __syncthreads();
    __shared__ float fsum[HID], fmax_[HID];
    if (threadIdx.x < HID) {
        int f = threadIdx.x;
        fsum[f] = psum[0][f] + psum[1][f] + psum[2][f] + psum[3][f];
        fmax_[f] = fmaxf(fmaxf(pmax[0][f], pmax[1][f]), fmaxf(pmax[2][f], pmax[3][f]));
    }
    __syncthreads();
    if (threadIdx.x < NC) {
        int c = threadIdx.x;
        float cnt = (float)(hi - lo);
        float inv = 1.f / fmaxf(cnt, 1.f);
        float o = blin[c];
#pragma unroll
        for (int f = 0; f < HID; ++f) {
            o += fmax_[f] * Wlin[f * NC + c];
            o += (fsum[f] * inv) * Wlin[(HID + f) * NC + c];
        }
        out[g * NC + c] = o;
    }
}

extern "C" void kernel_launch(void* const* d_in, const int* in_sizes, int n_in,
                              void* d_out, int out_size, void* d_ws, size_t ws_size,
                              hipStream_t stream) {
    const float* x   = (const float*)d_in[0];
    const int*   ei  = (const int*)d_in[1];
    const int*   bat = (const int*)d_in[2];
    const float* ew  = (const float*)d_in[3];
    const float* W1a = (const float*)d_in[4];
    const float* b1a = (const float*)d_in[5];
    const float* W1b = (const float*)d_in[6];
    const float* b1b = (const float*)d_in[7];
    const float* W2a = (const float*)d_in[8];
    const float* b2a = (const float*)d_in[9];
    const float* W2b = (const float*)d_in[10];
    const float* b2b = (const float*)d_in[11];
    const float* W3a = (const float*)d_in[12];
    const float* b3a = (const float*)d_in[13];
    const float* W3b = (const float*)d_in[14];
    const float* b3b = (const float*)d_in[15];
    const float* Wlin = (const float*)d_in[16];
    const float* blin = (const float*)d_in[17];

    const int* src = ei;
    const int* dst = ei + NE;

    dim3 blk(256);
    dim3 gN((NN + 255) / 256);
    dim3 gE((NE + 255) / 256);
    dim3 gQ(((size_t)NN * 4 + 255) / 256);

    size_t szT    = (size_t)NN * HID * sizeof(float);         // 8 MB (fallback)
    size_t szCsr  = (size_t)NE * sizeof(int2);                // 25.6 MB
    size_t szOff  = ((size_t)(NN + 1) * sizeof(int) + 15) & ~(size_t)15;
    size_t szGh   = (size_t)NB1 * NBLK1 * sizeof(int);        // 1.6 MB
    size_t szGb   = (size_t)NBLK1 * NB1P * sizeof(int);       // 1.6 MB
    size_t szSm   = 2048;
    size_t szTh   = (size_t)NN * HID * sizeof(__half);        // 4 MB
    size_t szPart = szCsr > 2 * szTh ? szCsr : 2 * szTh;      // part ∪ (T0h,T1h)
    size_t need_radix = szCsr + szOff + szGh + szGb + 2 * szSm + szPart;

    if (ws_size >= need_radix) {
        char* p = (char*)d_ws;
        int2* csr    = (int2*)p;  p += szCsr;
        int*  offv   = (int*)p;   p += szOff;
        int*  ghist  = (int*)p;   p += szGh;
        int*  gbase  = (int*)p;   p += szGb;
        int*  bsum   = (int*)p;   p += szSm;
        int*  bstart = (int*)p;   p += szSm;
        int2* part   = (int2*)p;             // dead after k_p2; then hosts T0h,T1h
        __half* T0h = (__half*)part;
        __half* T1h = T0h + (size_t)NN * HID;

        // ---- build CSR (two-level counting sort, once; reused by 3 layers) ----
        k_p1count<<<NBLK1, blk, 0, stream>>>(dst, ghist);
        k_breduceB<<<NB1, blk, 0, stream>>>(ghist, bsum);
        k_bscanB<<<1, blk, 0, stream>>>(bsum, bstart);
        k_bbase<<<NB1, blk, 0, stream>>>(ghist, bstart, gbase);
        k_p1scatter<<<NBLK1, blk, 0, stream>>>(src, dst, ew, gbase, part);
        k_p2<<<NB1, blk, 0, stream>>>(part, bstart, csr, offv);

        // ---- fused layers (f16 message tables, L2-resident) ----
        k_in_gemm_h<<<gN, blk, 0, stream>>>(x, W1a, T0h);
        k_layer<false><<<gQ, blk, 0, stream>>>(offv, csr, T0h, b1a, W1b, b1b, W2a, T1h);
        k_layer<false><<<gQ, blk, 0, stream>>>(offv, csr, T1h, b2a, W2b, b2b, W3a, T0h);
        k_layer<true><<<gQ, blk, 0, stream>>>(offv, csr, T0h, b3a, W3b, b3b, nullptr, T1h);

        k_pool_h<<<NG, blk, 0, stream>>>(T1h, bat, Wlin, blin, (float*)d_out);
    } else {
        // fallback: fp32 atomic scatter path
        char* p = (char*)d_ws;
        float* T0 = (float*)p;  p += szT;
        float* T1 = (float*)p;

        k_in_gemm<<<gN, blk, 0, stream>>>(x, W1a, T0);
        hipMemsetAsync(T1, 0, szT, stream);
        k_scatter<<<gE, blk, 0, stream>>>(src, dst, ew, T0, T1);
        k_node<false><<<gN, blk, 0, stream>>>(T1, b1a, W1b, b1b, W2a, T0);
        hipMemsetAsync(T1, 0, szT, stream);
        k_scatter<<<gE, blk, 0, stream>>>(src, dst, ew, T0, T1);
        k_node<false><<<gN, blk, 0, stream>>>(T1, b2a, W2b, b2b, W3a, T0);
        hipMemsetAsync(T1, 0, szT, stream);
        k_scatter<<<gE, blk, 0, stream>>>(src, dst, ew, T0, T1);
        k_node<true><<<gN, blk, 0, stream>>>(T1, b3a, W3b, b3b, nullptr, T0);
        k_pool<<<NG, blk, 0, stream>>>(T0, bat, Wlin, blin, (float*)d_out);
    }
}